// Round 1
// baseline (240.174 us; speedup 1.0000x reference)
//
#include <hip/hip_runtime.h>

// Problem constants (from reference setup_inputs)
constexpr int B  = 32;
constexpr int C  = 3;
constexpr int H  = 512;
constexpr int W  = 512;
constexpr int HP = H / 4;   // 128
constexpr int WP = W / 4;   // 128
constexpr int NP = B * HP * WP;  // 524288 pooled pixels

// Stage 1: p[b,py,px] = (1/48) * sum_{c=0..2, 4x4 window} (x - pred)
// (channel-mean followed by 4x4 avg pool of the difference; linearity lets us
// fuse the two pools and the subtraction.)
__global__ __launch_bounds__(256) void pool_diff_kernel(
        const float* __restrict__ x,
        const float* __restrict__ pred,
        float* __restrict__ p) {
    int idx = blockIdx.x * blockDim.x + threadIdx.x;
    if (idx >= NP) return;
    int px = idx & (WP - 1);          // WP=128 -> power of 2
    int py = (idx >> 7) & (HP - 1);
    int b  = idx >> 14;

    size_t base = (((size_t)b * C) * H + (size_t)py * 4) * W + (size_t)px * 4;
    float s = 0.0f;
    #pragma unroll
    for (int c = 0; c < C; ++c) {
        const float4* xb = (const float4*)(x    + base + (size_t)c * H * W);
        const float4* pb = (const float4*)(pred + base + (size_t)c * H * W);
        #pragma unroll
        for (int r = 0; r < 4; ++r) {
            float4 xv = xb[r * (W / 4)];
            float4 pv = pb[r * (W / 4)];
            s += (xv.x - pv.x) + (xv.y - pv.y) + (xv.z - pv.z) + (xv.w - pv.w);
        }
    }
    p[idx] = s * (1.0f / 48.0f);
}

// Stage 2: d0=c-left, d1=c-right, d2=c-up, d3=c-down (zero padding),
// accumulate sum of squares, reduce, atomicAdd scaled partial into out[0].
__global__ __launch_bounds__(256) void grad_loss_kernel(
        const float* __restrict__ p,
        float* __restrict__ out) {
    int idx = blockIdx.x * blockDim.x + threadIdx.x;
    float acc = 0.0f;
    if (idx < NP) {
        int px = idx & (WP - 1);
        int py = (idx >> 7) & (HP - 1);
        float c = p[idx];
        float l = (px > 0)      ? p[idx - 1]  : 0.0f;
        float r = (px < WP - 1) ? p[idx + 1]  : 0.0f;
        float u = (py > 0)      ? p[idx - WP] : 0.0f;
        float d = (py < HP - 1) ? p[idx + WP] : 0.0f;
        float g0 = c - l, g1 = c - r, g2 = c - u, g3 = c - d;
        acc = g0 * g0 + g1 * g1 + g2 * g2 + g3 * g3;
    }
    // wave64 shuffle reduction
    #pragma unroll
    for (int off = 32; off > 0; off >>= 1)
        acc += __shfl_down(acc, off, 64);

    __shared__ float ws_red[4];
    int lane = threadIdx.x & 63;
    int wid  = threadIdx.x >> 6;
    if (lane == 0) ws_red[wid] = acc;
    __syncthreads();
    if (threadIdx.x == 0) {
        float s = ws_red[0] + ws_red[1] + ws_red[2] + ws_red[3];
        atomicAdd(out, s * (1.0f / (float)NP));
    }
}

extern "C" void kernel_launch(void* const* d_in, const int* in_sizes, int n_in,
                              void* d_out, int out_size, void* d_ws, size_t ws_size,
                              hipStream_t stream) {
    const float* x    = (const float*)d_in[0];
    const float* pred = (const float*)d_in[1];
    float* out = (float*)d_out;
    float* p   = (float*)d_ws;   // NP floats = 2 MB scratch

    // d_out is poisoned 0xAA before every launch — zero it (capture-safe).
    hipMemsetAsync(out, 0, sizeof(float), stream);

    int threads = 256;
    int blocks  = (NP + threads - 1) / threads;  // 2048
    pool_diff_kernel<<<blocks, threads, 0, stream>>>(x, pred, p);
    grad_loss_kernel<<<blocks, threads, 0, stream>>>(p, out);
}

// Round 2
// 240.125 us; speedup vs baseline: 1.0002x; 1.0002x over previous
//
#include <hip/hip_runtime.h>

// Problem constants (from reference setup_inputs)
constexpr int B  = 32;
constexpr int C  = 3;
constexpr int H  = 512;
constexpr int W  = 512;
constexpr int HP = H / 4;   // 128
constexpr int WP = W / 4;   // 128
constexpr int NP = B * HP * WP;  // 524288 pooled pixels (= 2048 blocks x 256)

// Stage 1: p[b,py,px] = (1/48) * sum_{c=0..2, 4x4 window} (x - pred)
// Loads are staged into explicit float4 arrays so the compiler issues all 24
// global_load_dwordx4 back-to-back (MLP), instead of serializing on a scalar
// accumulator chain with 16 VGPRs (round-1 failure mode: 1.37 TB/s, latency-bound).
__global__ __launch_bounds__(256) void pool_diff_kernel(
        const float* __restrict__ x,
        const float* __restrict__ pred,
        float* __restrict__ p) {
    int idx = blockIdx.x * blockDim.x + threadIdx.x;   // grid sized exactly NP
    int px = idx & (WP - 1);
    int py = (idx >> 7) & (HP - 1);
    int b  = idx >> 14;

    size_t base = (((size_t)b * C) * H + (size_t)py * 4) * W + (size_t)px * 4;

    float4 xv[12], pv[12];
    #pragma unroll
    for (int c = 0; c < C; ++c) {
        #pragma unroll
        for (int r = 0; r < 4; ++r) {
            size_t off = base + (size_t)c * H * W + (size_t)r * W;
            xv[c * 4 + r] = *(const float4*)(x + off);
            pv[c * 4 + r] = *(const float4*)(pred + off);
        }
    }

    // Independent partial sums to shorten the dependency chain.
    float s0 = 0.f, s1 = 0.f, s2 = 0.f, s3 = 0.f;
    #pragma unroll
    for (int i = 0; i < 12; i += 4) {
        s0 += (xv[i+0].x - pv[i+0].x) + (xv[i+0].y - pv[i+0].y) + (xv[i+0].z - pv[i+0].z) + (xv[i+0].w - pv[i+0].w);
        s1 += (xv[i+1].x - pv[i+1].x) + (xv[i+1].y - pv[i+1].y) + (xv[i+1].z - pv[i+1].z) + (xv[i+1].w - pv[i+1].w);
        s2 += (xv[i+2].x - pv[i+2].x) + (xv[i+2].y - pv[i+2].y) + (xv[i+2].z - pv[i+2].z) + (xv[i+2].w - pv[i+2].w);
        s3 += (xv[i+3].x - pv[i+3].x) + (xv[i+3].y - pv[i+3].y) + (xv[i+3].z - pv[i+3].z) + (xv[i+3].w - pv[i+3].w);
    }
    p[idx] = (s0 + s1 + s2 + s3) * (1.0f / 48.0f);
}

// Stage 2: four neighbor differences (zero padding), sum of squares,
// wave shuffle reduce -> LDS -> one atomicAdd per block (pre-scaled).
__global__ __launch_bounds__(256) void grad_loss_kernel(
        const float* __restrict__ p,
        float* __restrict__ out) {
    int idx = blockIdx.x * blockDim.x + threadIdx.x;
    float acc = 0.0f;
    if (idx < NP) {
        int px = idx & (WP - 1);
        int py = (idx >> 7) & (HP - 1);
        float c = p[idx];
        float l = (px > 0)      ? p[idx - 1]  : 0.0f;
        float r = (px < WP - 1) ? p[idx + 1]  : 0.0f;
        float u = (py > 0)      ? p[idx - WP] : 0.0f;
        float d = (py < HP - 1) ? p[idx + WP] : 0.0f;
        float g0 = c - l, g1 = c - r, g2 = c - u, g3 = c - d;
        acc = g0 * g0 + g1 * g1 + g2 * g2 + g3 * g3;
    }
    #pragma unroll
    for (int off = 32; off > 0; off >>= 1)
        acc += __shfl_down(acc, off, 64);

    __shared__ float ws_red[4];
    int lane = threadIdx.x & 63;
    int wid  = threadIdx.x >> 6;
    if (lane == 0) ws_red[wid] = acc;
    __syncthreads();
    if (threadIdx.x == 0) {
        float s = ws_red[0] + ws_red[1] + ws_red[2] + ws_red[3];
        atomicAdd(out, s * (1.0f / (float)NP));
    }
}

extern "C" void kernel_launch(void* const* d_in, const int* in_sizes, int n_in,
                              void* d_out, int out_size, void* d_ws, size_t ws_size,
                              hipStream_t stream) {
    const float* x    = (const float*)d_in[0];
    const float* pred = (const float*)d_in[1];
    float* out = (float*)d_out;
    float* p   = (float*)d_ws;   // NP floats = 2 MB scratch

    // d_out is poisoned 0xAA before every launch — zero it (capture-safe).
    hipMemsetAsync(out, 0, sizeof(float), stream);

    int threads = 256;
    int blocks  = NP / threads;  // 2048 exactly
    pool_diff_kernel<<<blocks, threads, 0, stream>>>(x, pred, p);
    grad_loss_kernel<<<blocks, threads, 0, stream>>>(p, out);
}